// Round 21
// baseline (222.209 us; speedup 1.0000x reference)
//
#include <hip/hip_runtime.h>

typedef __attribute__((ext_vector_type(8))) short bf16x8;
typedef __attribute__((ext_vector_type(4))) float f32x4;

constexpr int NB = 16;    // bases
constexpr int REFF = 9;   // relations
constexpr int NXCD = 8;   // MI355X XCDs

__device__ __forceinline__ unsigned short f2bf(float f) {
  unsigned u = __float_as_uint(f);
  u += 0x7FFFu + ((u >> 16) & 1u);          // round-to-nearest-even
  return (unsigned short)(u >> 16);
}
__device__ __forceinline__ float bf2f(short s) {
  return __uint_as_float(((unsigned)(unsigned short)s) << 16);
}
__device__ __forceinline__ float bflo(unsigned u) {
  return __uint_as_float(u << 16);
}
__device__ __forceinline__ float bfhi(unsigned u) {
  return __uint_as_float(u & 0xFFFF0000u);
}

// ---------------- merged: histogram + prep (Xbf, W1p, W2p) ----------------
__device__ __forceinline__ unsigned short pack_w_one(const float* __restrict__ comps,
                                                     const float* __restrict__ bases,
                                                     int idx, int NTI, int NTOT) {
  int j = idx & 7;
  int lane = (idx >> 3) & 63;
  int ni = (idx >> 9) % NTI;
  int t = (idx >> 9) / NTI;        // r*8 + ks
  int ks = t & 7;
  int r = t >> 3;
  int k = ks * 32 + ((lane >> 4) << 3) + j;
  int n = ni * 16 + (lane & 15);
  float acc = 0.f;
#pragma unroll
  for (int b = 0; b < NB; ++b)
    acc += comps[r * NB + b] * bases[(size_t)b * 256 * NTOT + (size_t)k * NTOT + n];
  return f2bf(acc);
}

__global__ void hist_prep_kernel(const int* __restrict__ rows,
                                 int* __restrict__ deg1, int E,
                                 const float* __restrict__ features,
                                 unsigned short* __restrict__ Xbf,
                                 const float* __restrict__ comps1,
                                 const float* __restrict__ bases1,
                                 unsigned short* __restrict__ W1p,
                                 const float* __restrict__ comps2,
                                 const float* __restrict__ bases2,
                                 unsigned short* __restrict__ W2p, int N) {
  int idx = blockIdx.x * 256 + threadIdx.x;
  if (idx < E) atomicAdd(&deg1[rows[idx]], 1);
  const int n4 = N * 64;                 // float4 units of features
  const int PW1 = REFF * 8 * 16 * 512;   // 589824
  const int PW2 = REFF * 8 * 2 * 512;    // 73728
  if (idx < n4) {
    float4 f = reinterpret_cast<const float4*>(features)[idx];
    ushort4 o;
    o.x = f2bf(f.x); o.y = f2bf(f.y); o.z = f2bf(f.z); o.w = f2bf(f.w);
    reinterpret_cast<ushort4*>(Xbf)[idx] = o;
  } else if (idx < n4 + PW1) {
    int i = idx - n4;
    W1p[i] = pack_w_one(comps1, bases1, i, 16, 256);
  } else if (idx < n4 + PW1 + PW2) {
    int i = idx - n4 - PW1;
    W2p[i] = pack_w_one(comps2, bases2, i, 2, 32);
  }
}

// ---------------- scan: pass 1 (block sums) + merged pass 2/3 ----------------
__global__ void scan1_kernel(const int* __restrict__ deg, int* __restrict__ bsum,
                             int NR) {
  __shared__ int s[256];
  int t = threadIdx.x;
  int base = blockIdx.x * 1024 + t * 4;
  int acc = 0;
#pragma unroll
  for (int q = 0; q < 4; ++q)
    if (base + q < NR) acc += deg[base + q];
  s[t] = acc;
  __syncthreads();
  for (int off = 128; off > 0; off >>= 1) {
    if (t < off) s[t] += s[t + off];
    __syncthreads();
  }
  if (t == 0) bsum[blockIdx.x] = s[0];
}

__global__ void scan23_kernel(const int* __restrict__ deg,
                              const int* __restrict__ bsum,
                              int* __restrict__ ptr, int NR, int E) {
  __shared__ int s[256];
  __shared__ int sbase;
  int t = threadIdx.x;
  int b = blockIdx.x;
  int part = 0;
  for (int i = t; i < b; i += 256) part += bsum[i];
  s[t] = part;
  __syncthreads();
  for (int off = 128; off > 0; off >>= 1) {
    if (t < off) s[t] += s[t + off];
    __syncthreads();
  }
  if (t == 0) sbase = s[0];
  __syncthreads();
  int base0 = sbase;
  __syncthreads();
  int base = b * 1024 + t * 4;
  int d[4];
#pragma unroll
  for (int q = 0; q < 4; ++q)
    d[q] = (base + q < NR) ? deg[base + q] : 0;
  int tsum = d[0] + d[1] + d[2] + d[3];
  s[t] = tsum;
  __syncthreads();
  for (int off = 1; off < 256; off <<= 1) {
    int x = (t >= off) ? s[t - off] : 0;
    __syncthreads();
    s[t] += x;
    __syncthreads();
  }
  int off0 = base0 + s[t] - tsum;
#pragma unroll
  for (int q = 0; q < 4; ++q) {
    if (base + q < NR) ptr[base + q] = off0;
    off0 += d[q];
  }
  if (b == 0 && t == 0) ptr[NR] = E;
}

// fill: payload = src col only (val = 1/deg recomputed from ptr1 degree — exact)
__global__ void fill_kernel(const int* __restrict__ rows,
                            const int* __restrict__ cols,
                            int* __restrict__ deg1, const int* __restrict__ ptr1,
                            int* __restrict__ pay1, int E) {
  int e = blockIdx.x * 256 + threadIdx.x;
  if (e >= E) return;
  int g = rows[e];
  int o1 = atomicSub(&deg1[g], 1);
  pay1[ptr1[g] + o1 - 1] = cols[e];
}

// ---------------- fused layer 1 + layer-2 transform ----------------
// Quarter-wave owns one row. T14 async split: ISSUE(r+1) loads first <=2 edges'
// X rows into regs during MFMA(r); FINISH(r) consumes regs + synchronous tail.
__global__ __launch_bounds__(512, 8)
void fused_l1(const int* __restrict__ pay1, const int* __restrict__ ptr1,
              const unsigned short* __restrict__ Xbf,
              const unsigned short* __restrict__ W1p,
              const float* __restrict__ bias1,
              const unsigned short* __restrict__ W2p,
              unsigned short* __restrict__ Y2, int N, int nwg) {
  __shared__ char smem[32 * 1024];
  char* tile = smem;                 // 16 KB A-tile / out1 tile
  unsigned short* y2s = reinterpret_cast<unsigned short*>(smem + 16 * 1024); // 16 KB
  const int tid = threadIdx.x;
  const int w = tid >> 6, lane = tid & 63;
  const int l15 = lane & 15, kg = lane >> 4;
  const int qu = tid >> 4, l16 = tid & 15;

  // XCD-aware bijective swizzle (m204): contiguous chunk per XCD
  int bid;
  {
    int q = nwg / NXCD, rem = nwg % NXCD;
    int xcd = blockIdx.x % NXCD, idx = blockIdx.x / NXCD;
    bid = (xcd < rem ? xcd * (q + 1) : rem * (q + 1) + (xcd - rem) * q) + idx;
  }
  const int node0 = bid * 32;
  const int node = node0 + qu;      // this quarter-wave's row
  const bool vnode = node < N;

  f32x4 acc[2][2];
#pragma unroll
  for (int mi = 0; mi < 2; ++mi)
#pragma unroll
    for (int ni = 0; ni < 2; ++ni) acc[mi][ni] = (f32x4)(0.f);

  // prefetch state for one relation's row (first <=2 edges in regs)
  int pf_p0 = 0, pf_p1 = 0;
  float pf_s = 0.f;
  bf16x8 xa0, xa1, xb0, xb1;

  // ---- ISSUE(0) ----
  if (vnode) {
    int g = 0 * N + node;
    pf_p0 = ptr1[g]; pf_p1 = ptr1[g + 1];
    pf_s = (pf_p1 > pf_p0) ? 1.0f / (float)(pf_p1 - pf_p0) : 0.f;
    if (pf_p0 < pf_p1) {
      int c0 = pay1[pf_p0];
      const unsigned short* xr = Xbf + (size_t)c0 * 256 + l16 * 16;
      xa0 = *reinterpret_cast<const bf16x8*>(xr);
      xa1 = *reinterpret_cast<const bf16x8*>(xr + 8);
    }
    if (pf_p0 + 1 < pf_p1) {
      int c1 = pay1[pf_p0 + 1];
      const unsigned short* xr = Xbf + (size_t)c1 * 256 + l16 * 16;
      xb0 = *reinterpret_cast<const bf16x8*>(xr);
      xb1 = *reinterpret_cast<const bf16x8*>(xr + 8);
    }
  }

  for (int r = 0; r < REFF; ++r) {
    // ---- FINISH(r): accumulate prefetched edges + synchronous tail, write LDS ----
    {
      float a[16];
#pragma unroll
      for (int j = 0; j < 16; ++j) a[j] = 0.f;
      if (vnode && pf_p1 > pf_p0) {
#pragma unroll
        for (int j = 0; j < 8; ++j) { a[j] += bf2f(xa0[j]); a[8 + j] += bf2f(xa1[j]); }
        if (pf_p0 + 1 < pf_p1) {
#pragma unroll
          for (int j = 0; j < 8; ++j) { a[j] += bf2f(xb0[j]); a[8 + j] += bf2f(xb1[j]); }
        }
        // tail (deg > 2), 1-deep lookahead
        int p = pf_p0 + 2;
        int cn = 0;
        if (p < pf_p1) cn = pay1[p];
        for (; p < pf_p1; ++p) {
          int cc = cn;
          if (p + 1 < pf_p1) cn = pay1[p + 1];
          const unsigned short* xr = Xbf + (size_t)cc * 256 + l16 * 16;
          bf16x8 t0 = *reinterpret_cast<const bf16x8*>(xr);
          bf16x8 t1 = *reinterpret_cast<const bf16x8*>(xr + 8);
#pragma unroll
          for (int j = 0; j < 8; ++j) { a[j] += bf2f(t0[j]); a[8 + j] += bf2f(t1[j]); }
        }
      }
      float s = pf_s;
      uint4 o;
      o.x = (unsigned)f2bf(s * a[0]) | ((unsigned)f2bf(s * a[1]) << 16);
      o.y = (unsigned)f2bf(s * a[2]) | ((unsigned)f2bf(s * a[3]) << 16);
      o.z = (unsigned)f2bf(s * a[4]) | ((unsigned)f2bf(s * a[5]) << 16);
      o.w = (unsigned)f2bf(s * a[6]) | ((unsigned)f2bf(s * a[7]) << 16);
      *reinterpret_cast<uint4*>(tile + ((qu * 512 + l16 * 32) ^ ((qu & 7) << 4))) = o;
      o.x = (unsigned)f2bf(s * a[8]) | ((unsigned)f2bf(s * a[9]) << 16);
      o.y = (unsigned)f2bf(s * a[10]) | ((unsigned)f2bf(s * a[11]) << 16);
      o.z = (unsigned)f2bf(s * a[12]) | ((unsigned)f2bf(s * a[13]) << 16);
      o.w = (unsigned)f2bf(s * a[14]) | ((unsigned)f2bf(s * a[15]) << 16);
      *reinterpret_cast<uint4*>(tile + ((qu * 512 + l16 * 32 + 16) ^ ((qu & 7) << 4))) = o;
    }
    __syncthreads();   // tile(r) ready for all waves

    // ---- ISSUE(r+1): loads fly during MFMA(r) + barrier ----
    if (r + 1 < REFF && vnode) {
      int g = (r + 1) * N + node;
      pf_p0 = ptr1[g]; pf_p1 = ptr1[g + 1];
      pf_s = (pf_p1 > pf_p0) ? 1.0f / (float)(pf_p1 - pf_p0) : 0.f;
      if (pf_p0 < pf_p1) {
        int c0 = pay1[pf_p0];
        const unsigned short* xr = Xbf + (size_t)c0 * 256 + l16 * 16;
        xa0 = *reinterpret_cast<const bf16x8*>(xr);
        xa1 = *reinterpret_cast<const bf16x8*>(xr + 8);
      }
      if (pf_p0 + 1 < pf_p1) {
        int c1 = pay1[pf_p0 + 1];
        const unsigned short* xr = Xbf + (size_t)c1 * 256 + l16 * 16;
        xb0 = *reinterpret_cast<const bf16x8*>(xr);
        xb1 = *reinterpret_cast<const bf16x8*>(xr + 8);
      }
    }

    // ---- MFMA(r) ----
    __builtin_amdgcn_s_setprio(1);
#pragma unroll 2
    for (int ks = 0; ks < 8; ++ks) {
      bf16x8 a[2];
#pragma unroll
      for (int mi = 0; mi < 2; ++mi) {
        int row = mi * 16 + l15;
        int boff = (row * 512 + ks * 64 + (kg << 4)) ^ ((row & 7) << 4);
        a[mi] = *reinterpret_cast<const bf16x8*>(tile + boff);
      }
#pragma unroll
      for (int ni = 0; ni < 2; ++ni) {
        int niG = w * 2 + ni;
        bf16x8 b = *reinterpret_cast<const bf16x8*>(
            W1p + (((size_t)(r * 8 + ks) * 16 + niG) << 9) + lane * 8);
#pragma unroll
        for (int mi = 0; mi < 2; ++mi)
          acc[mi][ni] = __builtin_amdgcn_mfma_f32_16x16x32_bf16(a[mi], b,
                                                               acc[mi][ni], 0, 0, 0);
      }
    }
    __builtin_amdgcn_s_setprio(0);
    __syncthreads();   // MFMA(r) done reading tile before FINISH(r+1) overwrites
  }

  // epilogue: out1 tile = bf16(relu(acc + bias1)) -> tile (same swizzled layout)
#pragma unroll
  for (int mi = 0; mi < 2; ++mi) {
#pragma unroll
    for (int ni = 0; ni < 2; ++ni) {
      int col = (w * 2 + ni) * 16 + l15;
      float bb = bias1[col];
#pragma unroll
      for (int reg = 0; reg < 4; ++reg) {
        int row = mi * 16 + (kg << 2) + reg;
        float v = fmaxf(acc[mi][ni][reg] + bb, 0.f);
        int b = (row * 512 + col * 2) ^ ((row & 7) << 4);
        *reinterpret_cast<unsigned short*>(tile + b) = f2bf(v);
      }
    }
  }
  __syncthreads();

  // layer-2 transform, balanced: 18 half-jobs (rp, mih); wave w takes j = w, w+8, w+16
  unsigned short* ys = y2s + w * 1024;   // 2 KB per wave
  for (int j = w; j < 18; j += 8) {
    int rp = j >> 1, mih = j & 1;
    f32x4 a2[2];   // [nj]
    a2[0] = (f32x4)(0.f);
    a2[1] = (f32x4)(0.f);
    __builtin_amdgcn_s_setprio(1);
#pragma unroll
    for (int ks = 0; ks < 8; ++ks) {
      bf16x8 b0 = *reinterpret_cast<const bf16x8*>(
          W2p + (((size_t)(rp * 8 + ks) * 2 + 0) << 9) + lane * 8);
      bf16x8 b1 = *reinterpret_cast<const bf16x8*>(
          W2p + (((size_t)(rp * 8 + ks) * 2 + 1) << 9) + lane * 8);
      int row = mih * 16 + l15;
      int boff = (row * 512 + ks * 64 + (kg << 4)) ^ ((row & 7) << 4);
      bf16x8 a = *reinterpret_cast<const bf16x8*>(tile + boff);
      a2[0] = __builtin_amdgcn_mfma_f32_16x16x32_bf16(a, b0, a2[0], 0, 0, 0);
      a2[1] = __builtin_amdgcn_mfma_f32_16x16x32_bf16(a, b1, a2[1], 0, 0, 0);
    }
    __builtin_amdgcn_s_setprio(0);
#pragma unroll
    for (int reg = 0; reg < 4; ++reg) {
      int row16 = (kg << 2) + reg;           // 0..15
      ys[row16 * 32 + l15] = f2bf(a2[0][reg]);
      ys[row16 * 32 + 16 + l15] = f2bf(a2[1][reg]);
    }
    asm volatile("s_waitcnt lgkmcnt(0)" ::: "memory");
    {
      int row = lane >> 2;                   // 0..15
      int chunk = lane & 3;                  // 16B chunk within 64B row slice
      uint4 v = *reinterpret_cast<const uint4*>(&ys[row * 32 + chunk * 8]);
      int grow = node0 + mih * 16 + row;
      if (grow < N)
        *reinterpret_cast<uint4*>(Y2 + (size_t)grow * (REFF * 32) + rp * 32 + chunk * 8) = v;
    }
  }
}

// ---------------- layer 2 gather: out[n] = bias2 + sum_r (1/deg) sum_e Y2[src][r] ----------------
__global__ __launch_bounds__(512, 8)
void gather_out_kernel(const int* __restrict__ pay1,
                       const int* __restrict__ ptr1,
                       const unsigned short* __restrict__ Y2,
                       const float* __restrict__ bias2,
                       float* __restrict__ out, int N) {
  int wv = threadIdx.x >> 6;
  int lane = threadIdx.x & 63;
  int qw = lane >> 4, c = lane & 15;
  int n = blockIdx.x * 8 + wv;
  if (n >= N) return;
  float ax = 0.f, ay = 0.f;
  for (int r = qw; r < REFF; r += 4) {
    int g = r * N + n;
    int p0 = ptr1[g], p1 = ptr1[g + 1];
    if (p0 >= p1) continue;
    float v = 1.0f / (float)(p1 - p0);
    float sx = 0.f, sy = 0.f;
    int p = p0;
    for (; p + 2 <= p1; p += 2) {
      int c0 = pay1[p], c1 = pay1[p + 1];
      unsigned u0 = *reinterpret_cast<const unsigned*>(
          Y2 + (size_t)c0 * (REFF * 32) + r * 32 + c * 2);
      unsigned u1 = *reinterpret_cast<const unsigned*>(
          Y2 + (size_t)c1 * (REFF * 32) + r * 32 + c * 2);
      sx += bflo(u0) + bflo(u1);
      sy += bfhi(u0) + bfhi(u1);
    }
    if (p < p1) {
      int c0 = pay1[p];
      unsigned u0 = *reinterpret_cast<const unsigned*>(
          Y2 + (size_t)c0 * (REFF * 32) + r * 32 + c * 2);
      sx += bflo(u0);
      sy += bfhi(u0);
    }
    ax += v * sx;
    ay += v * sy;
  }
  ax += __shfl_xor(ax, 16); ay += __shfl_xor(ay, 16);
  ax += __shfl_xor(ax, 32); ay += __shfl_xor(ay, 32);
  if (lane < 16) {
    float2 o;
    o.x = ax + bias2[c * 2];
    o.y = ay + bias2[c * 2 + 1];
    reinterpret_cast<float2*>(out)[(size_t)n * 16 + c] = o;
  }
}

extern "C" void kernel_launch(void* const* d_in, const int* in_sizes, int n_in,
                              void* d_out, int out_size, void* d_ws, size_t ws_size,
                              hipStream_t stream) {
  const float* features = (const float*)d_in[0];
  const float* comps1   = (const float*)d_in[2];
  const float* bases1   = (const float*)d_in[3];
  const float* comps2   = (const float*)d_in[4];
  const float* bases2   = (const float*)d_in[5];
  const float* bias1    = (const float*)d_in[6];
  const float* bias2    = (const float*)d_in[7];
  const int* ver_rows   = (const int*)d_in[8];
  const int* ver_cols   = (const int*)d_in[9];

  const int N = in_sizes[0] / 256;   // 30000
  const int E = in_sizes[1];         // 500000
  const int NR = REFF * N;           // 270000
  const int NT = (NR + 1023) / 1024; // 264

  // ---- workspace layout (~38 MB; 64.1 MB proven-safe) ----
  char* p = (char*)d_ws;
  unsigned short* Xbf = (unsigned short*)p; p += (size_t)N * 256 * 2;        // 15.36 MB
  unsigned short* Y2  = (unsigned short*)p; p += (size_t)N * REFF * 32 * 2;  // 17.28 MB
  unsigned short* W1p = (unsigned short*)p; p += (size_t)REFF * 65536 * 2;   // 1.18 MB
  unsigned short* W2p = (unsigned short*)p; p += (size_t)REFF * 8192 * 2;    // 0.15 MB
  int* ptr1 = (int*)p;  p += (size_t)(NR + 4) * 4;
  int* pay1 = (int*)p;  p += (size_t)E * 4;
  int* deg1 = (int*)p;  p += (size_t)NR * 4;
  int* bsum = (int*)p;  p += 512 * 4;

  // ---- CSR build + prep ----
  hipMemsetAsync(deg1, 0, (size_t)NR * 4, stream);
  const int prep_total = N * 64 + REFF * 8 * 16 * 512 + REFF * 8 * 2 * 512;
  const int hp_grid = ((prep_total > E ? prep_total : E) + 255) / 256;
  hist_prep_kernel<<<hp_grid, 256, 0, stream>>>(ver_rows, deg1, E,
                                                features, Xbf,
                                                comps1, bases1, W1p,
                                                comps2, bases2, W2p, N);
  scan1_kernel<<<NT, 256, 0, stream>>>(deg1, bsum, NR);
  scan23_kernel<<<NT, 256, 0, stream>>>(deg1, bsum, ptr1, NR, E);
  fill_kernel<<<(E + 255) / 256, 256, 0, stream>>>(ver_rows, ver_cols,
                                                   deg1, ptr1, pay1, E);

  // ---- fused layer 1 + layer-2 transform ----
  const int nwg = (N + 31) / 32;
  fused_l1<<<nwg, 512, 0, stream>>>(pay1, ptr1, Xbf, W1p, bias1,
                                    W2p, Y2, N, nwg);
  // ---- layer 2 gather ----
  gather_out_kernel<<<(N + 7) / 8, 512, 0, stream>>>(pay1, ptr1, Y2, bias2,
                                                     (float*)d_out, N);
}

// Round 22
// 183.634 us; speedup vs baseline: 1.2101x; 1.2101x over previous
//
#include <hip/hip_runtime.h>

typedef __attribute__((ext_vector_type(8))) short bf16x8;
typedef __attribute__((ext_vector_type(4))) float f32x4;

constexpr int NB = 16;    // bases
constexpr int REFF = 9;   // relations
constexpr int NXCD = 8;   // MI355X XCDs

__device__ __forceinline__ unsigned short f2bf(float f) {
  unsigned u = __float_as_uint(f);
  u += 0x7FFFu + ((u >> 16) & 1u);          // round-to-nearest-even
  return (unsigned short)(u >> 16);
}
__device__ __forceinline__ float bf2f(short s) {
  return __uint_as_float(((unsigned)(unsigned short)s) << 16);
}
__device__ __forceinline__ float bflo(unsigned u) {
  return __uint_as_float(u << 16);
}
__device__ __forceinline__ float bfhi(unsigned u) {
  return __uint_as_float(u & 0xFFFF0000u);
}

// ---------------- merged: histogram + prep (Xbf, W1p, W2p) ----------------
__device__ __forceinline__ unsigned short pack_w_one(const float* __restrict__ comps,
                                                     const float* __restrict__ bases,
                                                     int idx, int NTI, int NTOT) {
  int j = idx & 7;
  int lane = (idx >> 3) & 63;
  int ni = (idx >> 9) % NTI;
  int t = (idx >> 9) / NTI;        // r*8 + ks
  int ks = t & 7;
  int r = t >> 3;
  int k = ks * 32 + ((lane >> 4) << 3) + j;
  int n = ni * 16 + (lane & 15);
  float acc = 0.f;
#pragma unroll
  for (int b = 0; b < NB; ++b)
    acc += comps[r * NB + b] * bases[(size_t)b * 256 * NTOT + (size_t)k * NTOT + n];
  return f2bf(acc);
}

__global__ void hist_prep_kernel(const int* __restrict__ rows,
                                 int* __restrict__ deg1, int E,
                                 const float* __restrict__ features,
                                 unsigned short* __restrict__ Xbf,
                                 const float* __restrict__ comps1,
                                 const float* __restrict__ bases1,
                                 unsigned short* __restrict__ W1p,
                                 const float* __restrict__ comps2,
                                 const float* __restrict__ bases2,
                                 unsigned short* __restrict__ W2p, int N) {
  int idx = blockIdx.x * 256 + threadIdx.x;
  if (idx < E) atomicAdd(&deg1[rows[idx]], 1);
  const int n4 = N * 64;                 // float4 units of features
  const int PW1 = REFF * 8 * 16 * 512;   // 589824
  const int PW2 = REFF * 8 * 2 * 512;    // 73728
  if (idx < n4) {
    float4 f = reinterpret_cast<const float4*>(features)[idx];
    ushort4 o;
    o.x = f2bf(f.x); o.y = f2bf(f.y); o.z = f2bf(f.z); o.w = f2bf(f.w);
    reinterpret_cast<ushort4*>(Xbf)[idx] = o;
  } else if (idx < n4 + PW1) {
    int i = idx - n4;
    W1p[i] = pack_w_one(comps1, bases1, i, 16, 256);
  } else if (idx < n4 + PW1 + PW2) {
    int i = idx - n4 - PW1;
    W2p[i] = pack_w_one(comps2, bases2, i, 2, 32);
  }
}

// ---------------- scan: pass 1 (block sums) + merged pass 2/3 ----------------
__global__ void scan1_kernel(const int* __restrict__ deg, int* __restrict__ bsum,
                             int NR) {
  __shared__ int s[256];
  int t = threadIdx.x;
  int base = blockIdx.x * 1024 + t * 4;
  int acc = 0;
#pragma unroll
  for (int q = 0; q < 4; ++q)
    if (base + q < NR) acc += deg[base + q];
  s[t] = acc;
  __syncthreads();
  for (int off = 128; off > 0; off >>= 1) {
    if (t < off) s[t] += s[t + off];
    __syncthreads();
  }
  if (t == 0) bsum[blockIdx.x] = s[0];
}

__global__ void scan23_kernel(const int* __restrict__ deg,
                              const int* __restrict__ bsum,
                              int* __restrict__ ptr, int NR, int E) {
  __shared__ int s[256];
  __shared__ int sbase;
  int t = threadIdx.x;
  int b = blockIdx.x;
  int part = 0;
  for (int i = t; i < b; i += 256) part += bsum[i];
  s[t] = part;
  __syncthreads();
  for (int off = 128; off > 0; off >>= 1) {
    if (t < off) s[t] += s[t + off];
    __syncthreads();
  }
  if (t == 0) sbase = s[0];
  __syncthreads();
  int base0 = sbase;
  __syncthreads();
  int base = b * 1024 + t * 4;
  int d[4];
#pragma unroll
  for (int q = 0; q < 4; ++q)
    d[q] = (base + q < NR) ? deg[base + q] : 0;
  int tsum = d[0] + d[1] + d[2] + d[3];
  s[t] = tsum;
  __syncthreads();
  for (int off = 1; off < 256; off <<= 1) {
    int x = (t >= off) ? s[t - off] : 0;
    __syncthreads();
    s[t] += x;
    __syncthreads();
  }
  int off0 = base0 + s[t] - tsum;
#pragma unroll
  for (int q = 0; q < 4; ++q) {
    if (base + q < NR) ptr[base + q] = off0;
    off0 += d[q];
  }
  if (b == 0 && t == 0) ptr[NR] = E;
}

// fill: payload = src col only (val = 1/deg recomputed from ptr1 degree — exact)
__global__ void fill_kernel(const int* __restrict__ rows,
                            const int* __restrict__ cols,
                            int* __restrict__ deg1, const int* __restrict__ ptr1,
                            int* __restrict__ pay1, int E) {
  int e = blockIdx.x * 256 + threadIdx.x;
  if (e >= E) return;
  int g = rows[e];
  int o1 = atomicSub(&deg1[g], 1);
  pay1[ptr1[g] + o1 - 1] = cols[e];
}

// ---------------- gather: QUARTER-wave owns ONE row (16 lanes x 32B) ----------------
__device__ __forceinline__ void gather_row_q(const int* __restrict__ pay,
                                             const int* __restrict__ ptr,
                                             const unsigned short* __restrict__ Xbf,
                                             char* lds, int node0, int N, int r,
                                             int qu, int l16) {
  const int rr = qu;                  // row within 32-row tile (0..31)
  const int node = node0 + rr;
  float acc[16];
#pragma unroll
  for (int j = 0; j < 16; ++j) acc[j] = 0.f;
  float s = 0.f;
  if (node < N) {
    int g = r * N + node;
    int p0 = ptr[g], p1 = ptr[g + 1];
    if (p1 > p0) s = 1.0f / (float)(p1 - p0);
    int cnext = 0;
    if (p0 < p1) cnext = pay[p0];
    for (int p = p0; p < p1; ++p) {
      int cc = cnext;
      if (p + 1 < p1) cnext = pay[p + 1];
      const unsigned short* xr = Xbf + (size_t)cc * 256 + l16 * 16;
      bf16x8 x0 = *reinterpret_cast<const bf16x8*>(xr);
      bf16x8 x1 = *reinterpret_cast<const bf16x8*>(xr + 8);
#pragma unroll
      for (int j = 0; j < 8; ++j) {
        acc[j] += bf2f(x0[j]);
        acc[8 + j] += bf2f(x1[j]);
      }
    }
  }
  uint4 o;
  o.x = (unsigned)f2bf(s * acc[0]) | ((unsigned)f2bf(s * acc[1]) << 16);
  o.y = (unsigned)f2bf(s * acc[2]) | ((unsigned)f2bf(s * acc[3]) << 16);
  o.z = (unsigned)f2bf(s * acc[4]) | ((unsigned)f2bf(s * acc[5]) << 16);
  o.w = (unsigned)f2bf(s * acc[6]) | ((unsigned)f2bf(s * acc[7]) << 16);
  *reinterpret_cast<uint4*>(lds + ((rr * 512 + l16 * 32) ^ ((rr & 7) << 4))) = o;
  o.x = (unsigned)f2bf(s * acc[8]) | ((unsigned)f2bf(s * acc[9]) << 16);
  o.y = (unsigned)f2bf(s * acc[10]) | ((unsigned)f2bf(s * acc[11]) << 16);
  o.z = (unsigned)f2bf(s * acc[12]) | ((unsigned)f2bf(s * acc[13]) << 16);
  o.w = (unsigned)f2bf(s * acc[14]) | ((unsigned)f2bf(s * acc[15]) << 16);
  *reinterpret_cast<uint4*>(lds + ((rr * 512 + l16 * 32 + 16) ^ ((rr & 7) << 4))) = o;
}

// ---------------- fused layer 1 + layer-2 transform (dbuf + swizzle + setprio) ----------------
__global__ __launch_bounds__(512, 8)
void fused_l1(const int* __restrict__ pay1, const int* __restrict__ ptr1,
              const unsigned short* __restrict__ Xbf,
              const unsigned short* __restrict__ W1p,
              const float* __restrict__ bias1,
              const unsigned short* __restrict__ W2p,
              unsigned short* __restrict__ Y2, int N, int nwg) {
  __shared__ char smem[32 * 1024];
  char* bufA = smem;                 // 16 KB tile buffer (even r)
  char* bufB = smem + 16 * 1024;     // 16 KB tile buffer (odd r); y2s after loop
  const int tid = threadIdx.x;
  const int w = tid >> 6, lane = tid & 63;
  const int l15 = lane & 15, kg = lane >> 4;
  const int qu = tid >> 4, l16 = tid & 15;

  // XCD-aware bijective swizzle (m204): contiguous chunk per XCD
  int bid;
  {
    int q = nwg / NXCD, rem = nwg % NXCD;
    int xcd = blockIdx.x % NXCD, idx = blockIdx.x / NXCD;
    bid = (xcd < rem ? xcd * (q + 1) : rem * (q + 1) + (xcd - rem) * q) + idx;
  }
  const int node0 = bid * 32;

  f32x4 acc[2][2];
#pragma unroll
  for (int mi = 0; mi < 2; ++mi)
#pragma unroll
    for (int ni = 0; ni < 2; ++ni) acc[mi][ni] = (f32x4)(0.f);

  // prologue: gather relation 0 into bufA
  gather_row_q(pay1, ptr1, Xbf, bufA, node0, N, 0, qu, l16);
  __syncthreads();

  for (int r = 0; r < REFF; ++r) {
    char* cur = (r & 1) ? bufB : bufA;
    // issue next relation's gather first (loads overlap this relation's MFMA)
    if (r + 1 < REFF) {
      char* nxt = ((r + 1) & 1) ? bufB : bufA;
      gather_row_q(pay1, ptr1, Xbf, nxt, node0, N, r + 1, qu, l16);
    }
    // MFMA phase from cur
    __builtin_amdgcn_s_setprio(1);
#pragma unroll 2
    for (int ks = 0; ks < 8; ++ks) {
      bf16x8 a[2];
#pragma unroll
      for (int mi = 0; mi < 2; ++mi) {
        int row = mi * 16 + l15;
        int boff = (row * 512 + ks * 64 + (kg << 4)) ^ ((row & 7) << 4);
        a[mi] = *reinterpret_cast<const bf16x8*>(cur + boff);
      }
#pragma unroll
      for (int ni = 0; ni < 2; ++ni) {
        int niG = w * 2 + ni;
        bf16x8 b = *reinterpret_cast<const bf16x8*>(
            W1p + (((size_t)(r * 8 + ks) * 16 + niG) << 9) + lane * 8);
#pragma unroll
        for (int mi = 0; mi < 2; ++mi)
          acc[mi][ni] = __builtin_amdgcn_mfma_f32_16x16x32_bf16(a[mi], b,
                                                               acc[mi][ni], 0, 0, 0);
      }
    }
    __builtin_amdgcn_s_setprio(0);
    __syncthreads();
  }

  // epilogue: out1 tile = bf16(relu(acc + bias1)) -> bufA (same swizzled layout)
#pragma unroll
  for (int mi = 0; mi < 2; ++mi) {
#pragma unroll
    for (int ni = 0; ni < 2; ++ni) {
      int col = (w * 2 + ni) * 16 + l15;
      float bb = bias1[col];
#pragma unroll
      for (int reg = 0; reg < 4; ++reg) {
        int row = mi * 16 + (kg << 2) + reg;
        float v = fmaxf(acc[mi][ni][reg] + bb, 0.f);
        int b = (row * 512 + col * 2) ^ ((row & 7) << 4);
        *reinterpret_cast<unsigned short*>(bufA + b) = f2bf(v);
      }
    }
  }
  __syncthreads();

  // layer-2 transform, balanced: 18 half-jobs (rp, mih); wave w takes j = w, w+8, w+16
  unsigned short* ys = reinterpret_cast<unsigned short*>(bufB) + w * 1024;  // 2 KB/wave
  for (int j = w; j < 18; j += 8) {
    int rp = j >> 1, mih = j & 1;
    f32x4 a2[2];   // [nj]
    a2[0] = (f32x4)(0.f);
    a2[1] = (f32x4)(0.f);
    __builtin_amdgcn_s_setprio(1);
#pragma unroll
    for (int ks = 0; ks < 8; ++ks) {
      bf16x8 b0 = *reinterpret_cast<const bf16x8*>(
          W2p + (((size_t)(rp * 8 + ks) * 2 + 0) << 9) + lane * 8);
      bf16x8 b1 = *reinterpret_cast<const bf16x8*>(
          W2p + (((size_t)(rp * 8 + ks) * 2 + 1) << 9) + lane * 8);
      int row = mih * 16 + l15;
      int boff = (row * 512 + ks * 64 + (kg << 4)) ^ ((row & 7) << 4);
      bf16x8 a = *reinterpret_cast<const bf16x8*>(bufA + boff);
      a2[0] = __builtin_amdgcn_mfma_f32_16x16x32_bf16(a, b0, a2[0], 0, 0, 0);
      a2[1] = __builtin_amdgcn_mfma_f32_16x16x32_bf16(a, b1, a2[1], 0, 0, 0);
    }
    __builtin_amdgcn_s_setprio(0);
    // stage 16x32 bf16 into wave-private LDS, then full-line stores
#pragma unroll
    for (int reg = 0; reg < 4; ++reg) {
      int row16 = (kg << 2) + reg;           // 0..15
      ys[row16 * 32 + l15] = f2bf(a2[0][reg]);
      ys[row16 * 32 + 16 + l15] = f2bf(a2[1][reg]);
    }
    asm volatile("s_waitcnt lgkmcnt(0)" ::: "memory");
    {
      int row = lane >> 2;                   // 0..15
      int chunk = lane & 3;                  // 16B chunk within 64B row slice
      uint4 v = *reinterpret_cast<const uint4*>(&ys[row * 32 + chunk * 8]);
      int grow = node0 + mih * 16 + row;
      if (grow < N)
        *reinterpret_cast<uint4*>(Y2 + (size_t)grow * (REFF * 32) + rp * 32 + chunk * 8) = v;
    }
  }
}

// ---------------- layer 2 gather: out[n] = bias2 + sum_r (1/deg) sum_e Y2[src][r] ----------------
// ptr pairs for the quarter-wave's relations hoisted up front (6 loads in flight)
__global__ __launch_bounds__(512, 8)
void gather_out_kernel(const int* __restrict__ pay1,
                       const int* __restrict__ ptr1,
                       const unsigned short* __restrict__ Y2,
                       const float* __restrict__ bias2,
                       float* __restrict__ out, int N) {
  int wv = threadIdx.x >> 6;
  int lane = threadIdx.x & 63;
  int qw = lane >> 4, c = lane & 15;
  int n = blockIdx.x * 8 + wv;
  if (n >= N) return;
  // hoisted ptr pair loads: relations qw, qw+4, qw+8 (qw+8 only valid for qw==0)
  int ga = qw * N + n;
  int gb = (qw + 4) * N + n;
  int p0a = ptr1[ga], p1a = ptr1[ga + 1];
  int p0b = ptr1[gb], p1b = ptr1[gb + 1];
  int p0c = 0, p1c = 0;
  if (qw == 0) {
    int gc = 8 * N + n;
    p0c = ptr1[gc];
    p1c = ptr1[gc + 1];
  }
  float ax = 0.f, ay = 0.f;
#pragma unroll
  for (int rr = 0; rr < 3; ++rr) {
    int p0 = (rr == 0) ? p0a : (rr == 1) ? p0b : p0c;
    int p1 = (rr == 0) ? p1a : (rr == 1) ? p1b : p1c;
    if (p0 >= p1) continue;
    int r = qw + rr * 4;
    float v = 1.0f / (float)(p1 - p0);
    float sx = 0.f, sy = 0.f;
    int p = p0;
    for (; p + 2 <= p1; p += 2) {
      int c0 = pay1[p], c1 = pay1[p + 1];
      unsigned u0 = *reinterpret_cast<const unsigned*>(
          Y2 + (size_t)c0 * (REFF * 32) + r * 32 + c * 2);
      unsigned u1 = *reinterpret_cast<const unsigned*>(
          Y2 + (size_t)c1 * (REFF * 32) + r * 32 + c * 2);
      sx += bflo(u0) + bflo(u1);
      sy += bfhi(u0) + bfhi(u1);
    }
    if (p < p1) {
      int c0 = pay1[p];
      unsigned u0 = *reinterpret_cast<const unsigned*>(
          Y2 + (size_t)c0 * (REFF * 32) + r * 32 + c * 2);
      sx += bflo(u0);
      sy += bfhi(u0);
    }
    ax += v * sx;
    ay += v * sy;
  }
  ax += __shfl_xor(ax, 16); ay += __shfl_xor(ay, 16);
  ax += __shfl_xor(ax, 32); ay += __shfl_xor(ay, 32);
  if (lane < 16) {
    float2 o;
    o.x = ax + bias2[c * 2];
    o.y = ay + bias2[c * 2 + 1];
    reinterpret_cast<float2*>(out)[(size_t)n * 16 + c] = o;
  }
}

extern "C" void kernel_launch(void* const* d_in, const int* in_sizes, int n_in,
                              void* d_out, int out_size, void* d_ws, size_t ws_size,
                              hipStream_t stream) {
  const float* features = (const float*)d_in[0];
  const float* comps1   = (const float*)d_in[2];
  const float* bases1   = (const float*)d_in[3];
  const float* comps2   = (const float*)d_in[4];
  const float* bases2   = (const float*)d_in[5];
  const float* bias1    = (const float*)d_in[6];
  const float* bias2    = (const float*)d_in[7];
  const int* ver_rows   = (const int*)d_in[8];
  const int* ver_cols   = (const int*)d_in[9];

  const int N = in_sizes[0] / 256;   // 30000
  const int E = in_sizes[1];         // 500000
  const int NR = REFF * N;           // 270000
  const int NT = (NR + 1023) / 1024; // 264

  // ---- workspace layout (~38 MB; 64.1 MB proven-safe) ----
  char* p = (char*)d_ws;
  unsigned short* Xbf = (unsigned short*)p; p += (size_t)N * 256 * 2;        // 15.36 MB
  unsigned short* Y2  = (unsigned short*)p; p += (size_t)N * REFF * 32 * 2;  // 17.28 MB
  unsigned short* W1p = (unsigned short*)p; p += (size_t)REFF * 65536 * 2;   // 1.18 MB
  unsigned short* W2p = (unsigned short*)p; p += (size_t)REFF * 8192 * 2;    // 0.15 MB
  int* ptr1 = (int*)p;  p += (size_t)(NR + 4) * 4;
  int* pay1 = (int*)p;  p += (size_t)E * 4;
  int* deg1 = (int*)p;  p += (size_t)NR * 4;
  int* bsum = (int*)p;  p += 512 * 4;

  // ---- CSR build + prep ----
  hipMemsetAsync(deg1, 0, (size_t)NR * 4, stream);
  const int prep_total = N * 64 + REFF * 8 * 16 * 512 + REFF * 8 * 2 * 512;
  const int hp_grid = ((prep_total > E ? prep_total : E) + 255) / 256;
  hist_prep_kernel<<<hp_grid, 256, 0, stream>>>(ver_rows, deg1, E,
                                                features, Xbf,
                                                comps1, bases1, W1p,
                                                comps2, bases2, W2p, N);
  scan1_kernel<<<NT, 256, 0, stream>>>(deg1, bsum, NR);
  scan23_kernel<<<NT, 256, 0, stream>>>(deg1, bsum, ptr1, NR, E);
  fill_kernel<<<(E + 255) / 256, 256, 0, stream>>>(ver_rows, ver_cols,
                                                   deg1, ptr1, pay1, E);

  // ---- fused layer 1 + layer-2 transform ----
  const int nwg = (N + 31) / 32;
  fused_l1<<<nwg, 512, 0, stream>>>(pay1, ptr1, Xbf, W1p, bias1,
                                    W2p, Y2, N, nwg);
  // ---- layer 2 gather ----
  gather_out_kernel<<<(N + 7) / 8, 512, 0, stream>>>(pay1, ptr1, Y2, bias2,
                                                     (float*)d_out, N);
}

// Round 23
// 183.334 us; speedup vs baseline: 1.2120x; 1.0016x over previous
//
#include <hip/hip_runtime.h>

typedef __attribute__((ext_vector_type(8))) short bf16x8;
typedef __attribute__((ext_vector_type(4))) float f32x4;
typedef __attribute__((ext_vector_type(2))) float f32x2;

constexpr int NB = 16;    // bases
constexpr int REFF = 9;   // relations
constexpr int NXCD = 8;   // MI355X XCDs

__device__ __forceinline__ unsigned short f2bf(float f) {
  unsigned u = __float_as_uint(f);
  u += 0x7FFFu + ((u >> 16) & 1u);          // round-to-nearest-even
  return (unsigned short)(u >> 16);
}
__device__ __forceinline__ float bflo(unsigned u) {
  return __uint_as_float(u << 16);
}
__device__ __forceinline__ float bfhi(unsigned u) {
  return __uint_as_float(u & 0xFFFF0000u);
}
// unpack 2 bf16 (packed in one dword) to f32 pair — feeds v_pk_add_f32
__device__ __forceinline__ f32x2 un2(unsigned u) {
  f32x2 t;
  t[0] = bflo(u);
  t[1] = bfhi(u);
  return t;
}
__device__ __forceinline__ unsigned pk2(float a, float b) {
  return (unsigned)f2bf(a) | ((unsigned)f2bf(b) << 16);
}

// ---------------- merged: histogram + prep (Xbf, W1p, W2p) ----------------
__device__ __forceinline__ unsigned short pack_w_one(const float* __restrict__ comps,
                                                     const float* __restrict__ bases,
                                                     int idx, int NTI, int NTOT) {
  int j = idx & 7;
  int lane = (idx >> 3) & 63;
  int ni = (idx >> 9) % NTI;
  int t = (idx >> 9) / NTI;        // r*8 + ks
  int ks = t & 7;
  int r = t >> 3;
  int k = ks * 32 + ((lane >> 4) << 3) + j;
  int n = ni * 16 + (lane & 15);
  float acc = 0.f;
#pragma unroll
  for (int b = 0; b < NB; ++b)
    acc += comps[r * NB + b] * bases[(size_t)b * 256 * NTOT + (size_t)k * NTOT + n];
  return f2bf(acc);
}

__global__ void hist_prep_kernel(const int* __restrict__ rows,
                                 int* __restrict__ deg1, int E,
                                 const float* __restrict__ features,
                                 unsigned short* __restrict__ Xbf,
                                 const float* __restrict__ comps1,
                                 const float* __restrict__ bases1,
                                 unsigned short* __restrict__ W1p,
                                 const float* __restrict__ comps2,
                                 const float* __restrict__ bases2,
                                 unsigned short* __restrict__ W2p, int N) {
  int idx = blockIdx.x * 256 + threadIdx.x;
  if (idx < E) atomicAdd(&deg1[rows[idx]], 1);
  const int n4 = N * 64;                 // float4 units of features
  const int PW1 = REFF * 8 * 16 * 512;   // 589824
  const int PW2 = REFF * 8 * 2 * 512;    // 73728
  if (idx < n4) {
    float4 f = reinterpret_cast<const float4*>(features)[idx];
    ushort4 o;
    o.x = f2bf(f.x); o.y = f2bf(f.y); o.z = f2bf(f.z); o.w = f2bf(f.w);
    reinterpret_cast<ushort4*>(Xbf)[idx] = o;
  } else if (idx < n4 + PW1) {
    int i = idx - n4;
    W1p[i] = pack_w_one(comps1, bases1, i, 16, 256);
  } else if (idx < n4 + PW1 + PW2) {
    int i = idx - n4 - PW1;
    W2p[i] = pack_w_one(comps2, bases2, i, 2, 32);
  }
}

// ---------------- scan: pass 1 (block sums) + merged pass 2/3 ----------------
__global__ void scan1_kernel(const int* __restrict__ deg, int* __restrict__ bsum,
                             int NR) {
  __shared__ int s[256];
  int t = threadIdx.x;
  int base = blockIdx.x * 1024 + t * 4;
  int acc = 0;
#pragma unroll
  for (int q = 0; q < 4; ++q)
    if (base + q < NR) acc += deg[base + q];
  s[t] = acc;
  __syncthreads();
  for (int off = 128; off > 0; off >>= 1) {
    if (t < off) s[t] += s[t + off];
    __syncthreads();
  }
  if (t == 0) bsum[blockIdx.x] = s[0];
}

__global__ void scan23_kernel(const int* __restrict__ deg,
                              const int* __restrict__ bsum,
                              int* __restrict__ ptr, int NR, int E) {
  __shared__ int s[256];
  __shared__ int sbase;
  int t = threadIdx.x;
  int b = blockIdx.x;
  int part = 0;
  for (int i = t; i < b; i += 256) part += bsum[i];
  s[t] = part;
  __syncthreads();
  for (int off = 128; off > 0; off >>= 1) {
    if (t < off) s[t] += s[t + off];
    __syncthreads();
  }
  if (t == 0) sbase = s[0];
  __syncthreads();
  int base0 = sbase;
  __syncthreads();
  int base = b * 1024 + t * 4;
  int d[4];
#pragma unroll
  for (int q = 0; q < 4; ++q)
    d[q] = (base + q < NR) ? deg[base + q] : 0;
  int tsum = d[0] + d[1] + d[2] + d[3];
  s[t] = tsum;
  __syncthreads();
  for (int off = 1; off < 256; off <<= 1) {
    int x = (t >= off) ? s[t - off] : 0;
    __syncthreads();
    s[t] += x;
    __syncthreads();
  }
  int off0 = base0 + s[t] - tsum;
#pragma unroll
  for (int q = 0; q < 4; ++q) {
    if (base + q < NR) ptr[base + q] = off0;
    off0 += d[q];
  }
  if (b == 0 && t == 0) ptr[NR] = E;
}

// fill: payload = src col only (val = 1/deg recomputed from ptr1 degree — exact)
__global__ void fill_kernel(const int* __restrict__ rows,
                            const int* __restrict__ cols,
                            int* __restrict__ deg1, const int* __restrict__ ptr1,
                            int* __restrict__ pay1, int E) {
  int e = blockIdx.x * 256 + threadIdx.x;
  if (e >= E) return;
  int g = rows[e];
  int o1 = atomicSub(&deg1[g], 1);
  pay1[ptr1[g] + o1 - 1] = cols[e];
}

// ---------------- gather: QUARTER-wave owns ONE row; packed-f32 accumulation ----------------
__device__ __forceinline__ void gather_row_q(const int* __restrict__ pay,
                                             const int* __restrict__ ptr,
                                             const unsigned short* __restrict__ Xbf,
                                             char* lds, int node0, int N, int r,
                                             int qu, int l16) {
  const int rr = qu;                  // row within 32-row tile (0..31)
  const int node = node0 + rr;
  f32x2 a8[8];
#pragma unroll
  for (int j = 0; j < 8; ++j) a8[j] = (f32x2)(0.f);
  float s = 0.f;
  if (node < N) {
    int g = r * N + node;
    int p0 = ptr[g], p1 = ptr[g + 1];
    if (p1 > p0) s = 1.0f / (float)(p1 - p0);
    int cnext = 0;
    if (p0 < p1) cnext = pay[p0];
    for (int p = p0; p < p1; ++p) {
      int cc = cnext;
      if (p + 1 < p1) cnext = pay[p + 1];
      const uint4* xr = reinterpret_cast<const uint4*>(Xbf + (size_t)cc * 256 + l16 * 16);
      uint4 u0 = xr[0];
      uint4 u1 = xr[1];
      a8[0] += un2(u0.x);
      a8[1] += un2(u0.y);
      a8[2] += un2(u0.z);
      a8[3] += un2(u0.w);
      a8[4] += un2(u1.x);
      a8[5] += un2(u1.y);
      a8[6] += un2(u1.z);
      a8[7] += un2(u1.w);
    }
  }
  uint4 o;
  o.x = pk2(s * a8[0][0], s * a8[0][1]);
  o.y = pk2(s * a8[1][0], s * a8[1][1]);
  o.z = pk2(s * a8[2][0], s * a8[2][1]);
  o.w = pk2(s * a8[3][0], s * a8[3][1]);
  *reinterpret_cast<uint4*>(lds + ((rr * 512 + l16 * 32) ^ ((rr & 7) << 4))) = o;
  o.x = pk2(s * a8[4][0], s * a8[4][1]);
  o.y = pk2(s * a8[5][0], s * a8[5][1]);
  o.z = pk2(s * a8[6][0], s * a8[6][1]);
  o.w = pk2(s * a8[7][0], s * a8[7][1]);
  *reinterpret_cast<uint4*>(lds + ((rr * 512 + l16 * 32 + 16) ^ ((rr & 7) << 4))) = o;
}

// ---------------- fused layer 1 + layer-2 transform (dbuf + swizzle + setprio) ----------------
__global__ __launch_bounds__(512, 8)
void fused_l1(const int* __restrict__ pay1, const int* __restrict__ ptr1,
              const unsigned short* __restrict__ Xbf,
              const unsigned short* __restrict__ W1p,
              const float* __restrict__ bias1,
              const unsigned short* __restrict__ W2p,
              unsigned short* __restrict__ Y2, int N, int nwg) {
  __shared__ char smem[32 * 1024];
  char* bufA = smem;                 // 16 KB tile buffer (even r)
  char* bufB = smem + 16 * 1024;     // 16 KB tile buffer (odd r); y2s after loop
  const int tid = threadIdx.x;
  const int w = tid >> 6, lane = tid & 63;
  const int l15 = lane & 15, kg = lane >> 4;
  const int qu = tid >> 4, l16 = tid & 15;

  // XCD-aware bijective swizzle (m204): contiguous chunk per XCD
  int bid;
  {
    int q = nwg / NXCD, rem = nwg % NXCD;
    int xcd = blockIdx.x % NXCD, idx = blockIdx.x / NXCD;
    bid = (xcd < rem ? xcd * (q + 1) : rem * (q + 1) + (xcd - rem) * q) + idx;
  }
  const int node0 = bid * 32;

  f32x4 acc[2][2];
#pragma unroll
  for (int mi = 0; mi < 2; ++mi)
#pragma unroll
    for (int ni = 0; ni < 2; ++ni) acc[mi][ni] = (f32x4)(0.f);

  // prologue: gather relation 0 into bufA
  gather_row_q(pay1, ptr1, Xbf, bufA, node0, N, 0, qu, l16);
  __syncthreads();

  for (int r = 0; r < REFF; ++r) {
    char* cur = (r & 1) ? bufB : bufA;
    // issue next relation's gather first (loads overlap this relation's MFMA)
    if (r + 1 < REFF) {
      char* nxt = ((r + 1) & 1) ? bufB : bufA;
      gather_row_q(pay1, ptr1, Xbf, nxt, node0, N, r + 1, qu, l16);
    }
    // MFMA phase from cur
    __builtin_amdgcn_s_setprio(1);
#pragma unroll 2
    for (int ks = 0; ks < 8; ++ks) {
      bf16x8 a[2];
#pragma unroll
      for (int mi = 0; mi < 2; ++mi) {
        int row = mi * 16 + l15;
        int boff = (row * 512 + ks * 64 + (kg << 4)) ^ ((row & 7) << 4);
        a[mi] = *reinterpret_cast<const bf16x8*>(cur + boff);
      }
#pragma unroll
      for (int ni = 0; ni < 2; ++ni) {
        int niG = w * 2 + ni;
        bf16x8 b = *reinterpret_cast<const bf16x8*>(
            W1p + (((size_t)(r * 8 + ks) * 16 + niG) << 9) + lane * 8);
#pragma unroll
        for (int mi = 0; mi < 2; ++mi)
          acc[mi][ni] = __builtin_amdgcn_mfma_f32_16x16x32_bf16(a[mi], b,
                                                               acc[mi][ni], 0, 0, 0);
      }
    }
    __builtin_amdgcn_s_setprio(0);
    __syncthreads();
  }

  // epilogue: out1 tile = bf16(relu(acc + bias1)) -> bufA (same swizzled layout)
#pragma unroll
  for (int mi = 0; mi < 2; ++mi) {
#pragma unroll
    for (int ni = 0; ni < 2; ++ni) {
      int col = (w * 2 + ni) * 16 + l15;
      float bb = bias1[col];
#pragma unroll
      for (int reg = 0; reg < 4; ++reg) {
        int row = mi * 16 + (kg << 2) + reg;
        float v = fmaxf(acc[mi][ni][reg] + bb, 0.f);
        int b = (row * 512 + col * 2) ^ ((row & 7) << 4);
        *reinterpret_cast<unsigned short*>(bufA + b) = f2bf(v);
      }
    }
  }
  __syncthreads();

  // layer-2 transform, balanced: 18 half-jobs (rp, mih); wave w takes j = w, w+8, w+16
  unsigned short* ys = reinterpret_cast<unsigned short*>(bufB) + w * 1024;  // 2 KB/wave
  for (int j = w; j < 18; j += 8) {
    int rp = j >> 1, mih = j & 1;
    f32x4 a2[2];   // [nj]
    a2[0] = (f32x4)(0.f);
    a2[1] = (f32x4)(0.f);
    __builtin_amdgcn_s_setprio(1);
#pragma unroll
    for (int ks = 0; ks < 8; ++ks) {
      bf16x8 b0 = *reinterpret_cast<const bf16x8*>(
          W2p + (((size_t)(rp * 8 + ks) * 2 + 0) << 9) + lane * 8);
      bf16x8 b1 = *reinterpret_cast<const bf16x8*>(
          W2p + (((size_t)(rp * 8 + ks) * 2 + 1) << 9) + lane * 8);
      int row = mih * 16 + l15;
      int boff = (row * 512 + ks * 64 + (kg << 4)) ^ ((row & 7) << 4);
      bf16x8 a = *reinterpret_cast<const bf16x8*>(bufA + boff);
      a2[0] = __builtin_amdgcn_mfma_f32_16x16x32_bf16(a, b0, a2[0], 0, 0, 0);
      a2[1] = __builtin_amdgcn_mfma_f32_16x16x32_bf16(a, b1, a2[1], 0, 0, 0);
    }
    __builtin_amdgcn_s_setprio(0);
    // stage 16x32 bf16 into wave-private LDS, then full-line stores
#pragma unroll
    for (int reg = 0; reg < 4; ++reg) {
      int row16 = (kg << 2) + reg;           // 0..15
      ys[row16 * 32 + l15] = f2bf(a2[0][reg]);
      ys[row16 * 32 + 16 + l15] = f2bf(a2[1][reg]);
    }
    asm volatile("s_waitcnt lgkmcnt(0)" ::: "memory");
    {
      int row = lane >> 2;                   // 0..15
      int chunk = lane & 3;                  // 16B chunk within 64B row slice
      uint4 v = *reinterpret_cast<const uint4*>(&ys[row * 32 + chunk * 8]);
      int grow = node0 + mih * 16 + row;
      if (grow < N)
        *reinterpret_cast<uint4*>(Y2 + (size_t)grow * (REFF * 32) + rp * 32 + chunk * 8) = v;
    }
  }
}

// ---------------- layer 2 gather: out[n] = bias2 + sum_r (1/deg) sum_e Y2[src][r] ----------------
// ptr pairs hoisted; packed-f32 accumulation
__global__ __launch_bounds__(512, 8)
void gather_out_kernel(const int* __restrict__ pay1,
                       const int* __restrict__ ptr1,
                       const unsigned short* __restrict__ Y2,
                       const float* __restrict__ bias2,
                       float* __restrict__ out, int N) {
  int wv = threadIdx.x >> 6;
  int lane = threadIdx.x & 63;
  int qw = lane >> 4, c = lane & 15;
  int n = blockIdx.x * 8 + wv;
  if (n >= N) return;
  // hoisted ptr pair loads: relations qw, qw+4, qw+8 (qw+8 only valid for qw==0)
  int ga = qw * N + n;
  int gb = (qw + 4) * N + n;
  int p0a = ptr1[ga], p1a = ptr1[ga + 1];
  int p0b = ptr1[gb], p1b = ptr1[gb + 1];
  int p0c = 0, p1c = 0;
  if (qw == 0) {
    int gc = 8 * N + n;
    p0c = ptr1[gc];
    p1c = ptr1[gc + 1];
  }
  float ax = 0.f, ay = 0.f;
#pragma unroll
  for (int rr = 0; rr < 3; ++rr) {
    int p0 = (rr == 0) ? p0a : (rr == 1) ? p0b : p0c;
    int p1 = (rr == 0) ? p1a : (rr == 1) ? p1b : p1c;
    if (p0 >= p1) continue;
    int r = qw + rr * 4;
    float v = 1.0f / (float)(p1 - p0);
    f32x2 sacc = (f32x2)(0.f);
    int p = p0;
    for (; p + 2 <= p1; p += 2) {
      int c0 = pay1[p], c1 = pay1[p + 1];
      unsigned u0 = *reinterpret_cast<const unsigned*>(
          Y2 + (size_t)c0 * (REFF * 32) + r * 32 + c * 2);
      unsigned u1 = *reinterpret_cast<const unsigned*>(
          Y2 + (size_t)c1 * (REFF * 32) + r * 32 + c * 2);
      sacc += un2(u0);
      sacc += un2(u1);
    }
    if (p < p1) {
      int c0 = pay1[p];
      unsigned u0 = *reinterpret_cast<const unsigned*>(
          Y2 + (size_t)c0 * (REFF * 32) + r * 32 + c * 2);
      sacc += un2(u0);
    }
    ax += v * sacc[0];
    ay += v * sacc[1];
  }
  ax += __shfl_xor(ax, 16); ay += __shfl_xor(ay, 16);
  ax += __shfl_xor(ax, 32); ay += __shfl_xor(ay, 32);
  if (lane < 16) {
    float2 o;
    o.x = ax + bias2[c * 2];
    o.y = ay + bias2[c * 2 + 1];
    reinterpret_cast<float2*>(out)[(size_t)n * 16 + c] = o;
  }
}

extern "C" void kernel_launch(void* const* d_in, const int* in_sizes, int n_in,
                              void* d_out, int out_size, void* d_ws, size_t ws_size,
                              hipStream_t stream) {
  const float* features = (const float*)d_in[0];
  const float* comps1   = (const float*)d_in[2];
  const float* bases1   = (const float*)d_in[3];
  const float* comps2   = (const float*)d_in[4];
  const float* bases2   = (const float*)d_in[5];
  const float* bias1    = (const float*)d_in[6];
  const float* bias2    = (const float*)d_in[7];
  const int* ver_rows   = (const int*)d_in[8];
  const int* ver_cols   = (const int*)d_in[9];

  const int N = in_sizes[0] / 256;   // 30000
  const int E = in_sizes[1];         // 500000
  const int NR = REFF * N;           // 270000
  const int NT = (NR + 1023) / 1024; // 264

  // ---- workspace layout (~38 MB; 64.1 MB proven-safe) ----
  char* p = (char*)d_ws;
  unsigned short* Xbf = (unsigned short*)p; p += (size_t)N * 256 * 2;        // 15.36 MB
  unsigned short* Y2  = (unsigned short*)p; p += (size_t)N * REFF * 32 * 2;  // 17.28 MB
  unsigned short* W1p = (unsigned short*)p; p += (size_t)REFF * 65536 * 2;   // 1.18 MB
  unsigned short* W2p = (unsigned short*)p; p += (size_t)REFF * 8192 * 2;    // 0.15 MB
  int* ptr1 = (int*)p;  p += (size_t)(NR + 4) * 4;
  int* pay1 = (int*)p;  p += (size_t)E * 4;
  int* deg1 = (int*)p;  p += (size_t)NR * 4;
  int* bsum = (int*)p;  p += 512 * 4;

  // ---- CSR build + prep ----
  hipMemsetAsync(deg1, 0, (size_t)NR * 4, stream);
  const int prep_total = N * 64 + REFF * 8 * 16 * 512 + REFF * 8 * 2 * 512;
  const int hp_grid = ((prep_total > E ? prep_total : E) + 255) / 256;
  hist_prep_kernel<<<hp_grid, 256, 0, stream>>>(ver_rows, deg1, E,
                                                features, Xbf,
                                                comps1, bases1, W1p,
                                                comps2, bases2, W2p, N);
  scan1_kernel<<<NT, 256, 0, stream>>>(deg1, bsum, NR);
  scan23_kernel<<<NT, 256, 0, stream>>>(deg1, bsum, ptr1, NR, E);
  fill_kernel<<<(E + 255) / 256, 256, 0, stream>>>(ver_rows, ver_cols,
                                                   deg1, ptr1, pay1, E);

  // ---- fused layer 1 + layer-2 transform ----
  const int nwg = (N + 31) / 32;
  fused_l1<<<nwg, 512, 0, stream>>>(pay1, ptr1, Xbf, W1p, bias1,
                                    W2p, Y2, N, nwg);
  // ---- layer 2 gather ----
  gather_out_kernel<<<(N + 7) / 8, 512, 0, stream>>>(pay1, ptr1, Y2, bias2,
                                                     (float*)d_out, N);
}